// Round 5
// baseline (112.460 us; speedup 1.0000x reference)
//
#include <hip/hip_runtime.h>
#include <hip/hip_cooperative_groups.h>

namespace cg = cooperative_groups;

// out[chw] = sum_b (prev_x[b,chw] > 0) * popcount_pos(curr_x[b])
//   prev_x: [128, 256, 28, 28] f32, curr_x: [128, 512, 14, 14] f32
// All values integer <= 128*100352 < 2^24 -> exact in fp32 in any order.
//
// R5: single cooperative dispatch. Pre-sync: each block counts a 25088-float
// curr slice (slices never straddle a batch: 100352 = 4*25088) AND builds
// prev-predicate bitmasks for its output columns -> both HBM streams overlap,
// no idle join. grid.sync() replaces R4's hand-rolled (hung) spin barrier.
// Post-sync: fold 512 counts -> s_sum[128] in LDS, weighted combine, store.

constexpr int NB       = 128;
constexpr int CURR_CHW = 512 * 14 * 14;        // 100352
constexpr int PREV_CHW = 256 * 28 * 28;        // 200704
constexpr int NBLK     = 512;                  // exactly 2 blocks / CU
constexpr int SLICE_V4 = CURR_CHW * NB / NBLK / 4;  // 6272 float4 per slice
constexpr int COLS0    = NBLK * 256;           // 131072 first-column units
constexpr int TWO_BLKS = (PREV_CHW - COLS0) / 256;  // 272 blocks own 2 columns

__global__ void __launch_bounds__(256)
fused_kernel(const float* __restrict__ prev, const float* __restrict__ curr,
             float* __restrict__ out, unsigned int* __restrict__ slots) {
    const int g = blockIdx.x;
    const int t = threadIdx.x;

    // ---- phase A: positive count of this block's curr slice ----
    {
        const float4* p4 = reinterpret_cast<const float4*>(curr) + (size_t)g * SLICE_V4;
        unsigned int c = 0;
        for (int i = t; i < SLICE_V4; i += 256) {
            const float4 v = p4[i];
            c += (v.x > 0.f) + (v.y > 0.f) + (v.z > 0.f) + (v.w > 0.f);
        }
        #pragma unroll
        for (int off = 32; off > 0; off >>= 1)
            c += __shfl_down(c, off, 64);
        __shared__ unsigned int wred[4];
        if ((t & 63) == 0) wred[t >> 6] = c;
        __syncthreads();
        if (t == 0)
            __hip_atomic_store(&slots[g], wred[0] + wred[1] + wred[2] + wred[3],
                               __ATOMIC_RELAXED, __HIP_MEMORY_SCOPE_AGENT);
    }

    // ---- phase B: predicate bitmasks (overlaps other blocks' phase A) ----
    const int col0 = g * 256 + t;              // scalar column, always valid
    const bool two = (g < TWO_BLKS);           // block-uniform second column
    unsigned int m0[4], m1[4];
    {
        const float* b0p = prev + col0;
        #pragma unroll
        for (int w = 0; w < 4; ++w) {          // w compile-time -> static regs
            unsigned int a = 0;
            #pragma unroll 16
            for (int bb = 0; bb < 32; ++bb)
                a |= (b0p[(size_t)(w * 32 + bb) * PREV_CHW] > 0.f ? 1u : 0u) << bb;
            m0[w] = a;
        }
        if (two) {
            const float* b1p = prev + col0 + COLS0;
            #pragma unroll
            for (int w = 0; w < 4; ++w) {
                unsigned int a = 0;
                #pragma unroll 16
                for (int bb = 0; bb < 32; ++bb)
                    a |= (b1p[(size_t)(w * 32 + bb) * PREV_CHW] > 0.f ? 1u : 0u) << bb;
                m1[w] = a;
            }
        } else {
            m1[0] = m1[1] = m1[2] = m1[3] = 0u;
        }
    }

    cg::this_grid().sync();

    // ---- phase C: fold 512 slice counts -> s_sum[128] (batch = slot/4) ----
    __shared__ float s_sum[NB];
    if (t < NB) {
        unsigned int s = 0;
        #pragma unroll
        for (int q = 0; q < 4; ++q)
            s += __hip_atomic_load(&slots[4 * t + q],
                                   __ATOMIC_RELAXED, __HIP_MEMORY_SCOPE_AGENT);
        s_sum[t] = (float)s;
    }
    __syncthreads();

    // ---- phase D: out[col] = sum_b bit * s[b], static indexing ----
    float o0 = 0.f, o1 = 0.f;
    #pragma unroll
    for (int w = 0; w < 4; ++w) {
        const unsigned int a0 = m0[w], a1 = m1[w];
        #pragma unroll
        for (int bb = 0; bb < 32; ++bb) {
            const float s = s_sum[w * 32 + bb];
            o0 += ((a0 >> bb) & 1u) ? s : 0.f;
            o1 += ((a1 >> bb) & 1u) ? s : 0.f;
        }
    }
    out[col0] = o0;
    if (two) out[col0 + COLS0] = o1;
}

// ---------- deterministic fallback (R3 two-kernel path, proven 31.3 us) ----
constexpr int CURR_V4 = CURR_CHW / 4;     // 25088
constexpr int QUARTER = CURR_V4 / 4;      // 6272
constexpr int PREV_V2 = PREV_CHW / 2;     // 100352

__global__ void __launch_bounds__(256)
count_pos_kernel(const float* __restrict__ curr, float* __restrict__ partial) {
    const int b = blockIdx.x, q = blockIdx.y;
    const float4* p = reinterpret_cast<const float4*>(curr)
                      + (size_t)b * CURR_V4 + (size_t)q * QUARTER;
    int cnt = 0;
    for (int i = threadIdx.x; i < QUARTER; i += 256) {
        const float4 v = p[i];
        cnt += (v.x > 0.f) + (v.y > 0.f) + (v.z > 0.f) + (v.w > 0.f);
    }
    #pragma unroll
    for (int off = 32; off > 0; off >>= 1)
        cnt += __shfl_down(cnt, off, 64);
    __shared__ int wsum[4];
    if ((threadIdx.x & 63) == 0) wsum[threadIdx.x >> 6] = cnt;
    __syncthreads();
    if (threadIdx.x == 0)
        partial[q * NB + b] = (float)(wsum[0] + wsum[1] + wsum[2] + wsum[3]);
}

__global__ void __launch_bounds__(128)
corr_kernel(const float* __restrict__ prev, const float* __restrict__ partial,
            float* __restrict__ out) {
    __shared__ float s_sum[NB];
    const int t = threadIdx.x;
    s_sum[t] = partial[t] + partial[NB + t] + partial[2 * NB + t] + partial[3 * NB + t];
    __syncthreads();
    const int u = blockIdx.x * 128 + t;
    const float2* pv = reinterpret_cast<const float2*>(prev) + u;
    float2 acc = make_float2(0.f, 0.f);
    #pragma unroll 16
    for (int b = 0; b < NB; ++b) {
        const float2 v = pv[(size_t)b * PREV_V2];
        const float s = s_sum[b];
        acc.x += (v.x > 0.f) ? s : 0.f;
        acc.y += (v.y > 0.f) ? s : 0.f;
    }
    reinterpret_cast<float2*>(out)[u] = acc;
}

extern "C" void kernel_launch(void* const* d_in, const int* in_sizes, int n_in,
                              void* d_out, int out_size, void* d_ws, size_t ws_size,
                              hipStream_t stream) {
    const float* prev = (const float*)d_in[0];
    const float* curr = (const float*)d_in[1];
    float* out = (float*)d_out;

    unsigned int* slots = (unsigned int*)d_ws;   // 512 u32, rewritten every call
    void* args[] = { (void*)&prev, (void*)&curr, (void*)&out, (void*)&slots };
    hipError_t err = hipLaunchCooperativeKernel((const void*)fused_kernel,
                                                dim3(NBLK), dim3(256),
                                                args, 0, stream);
    if (err != hipSuccess) {
        // deterministic fallback: proven two-kernel path
        float* partial = (float*)d_ws;
        count_pos_kernel<<<dim3(NB, 4), 256, 0, stream>>>(curr, partial);
        corr_kernel<<<PREV_V2 / 128, 128, 0, stream>>>(prev, partial, out);
    }
}

// Round 6
// 29.890 us; speedup vs baseline: 3.7625x; 3.7625x over previous
//
#include <hip/hip_runtime.h>

// out[chw] = sum_b (prev_x[b,chw] > 0) * popcount_pos(curr_x[b])
//   prev_x: [128, 256, 28, 28] f32, curr_x: [128, 512, 14, 14] f32
// All values integer <= 128*100352 < 2^24 -> exact in fp32 in any order.
//
// R6: back to the proven two-kernel structure (R5 coop fusion = 118us/dispatch
// even L3-resident -> grid.sync cost ~90us; abandoned). Changes vs R2/R3:
//  - k1: 1024 blocks (128 batches x 8 slices) -> finer tail at the k1->k2 join.
//  - k2: unroll 32 (256 B in flight per thread, ~2x R2/R3's MLP), 256-thread
//    blocks, 392 blocks = exact cover of 100352 float2 columns.
// A/B intent: if dur is flat vs R2's 30.76, the ~5 TB/s effective BW is the
// service ceiling for this access pattern -> roofline.

constexpr int NB       = 128;
constexpr int CURR_CHW = 512 * 14 * 14;   // 100352 floats per batch
constexpr int PREV_CHW = 256 * 28 * 28;   // 200704 floats per batch
constexpr int CURR_V4  = CURR_CHW / 4;    // 25088 float4 per batch
constexpr int NSLICE   = 8;               // k1 slices per batch
constexpr int SLICE_V4 = CURR_V4 / NSLICE; // 3136 float4 per (batch, slice)
constexpr int PREV_V2  = PREV_CHW / 2;    // 100352 float2 columns

// Kernel 1: partial positive-count of curr_x. grid = (128, 8) = 1024 blocks.
__global__ void __launch_bounds__(256)
count_pos_kernel(const float* __restrict__ curr, float* __restrict__ partial) {
    const int b = blockIdx.x, q = blockIdx.y;
    const float4* p = reinterpret_cast<const float4*>(curr)
                      + (size_t)b * CURR_V4 + (size_t)q * SLICE_V4;
    int cnt = 0;
    for (int i = threadIdx.x; i < SLICE_V4; i += 256) {
        const float4 v = p[i];
        cnt += (v.x > 0.f) + (v.y > 0.f) + (v.z > 0.f) + (v.w > 0.f);
    }
    #pragma unroll
    for (int off = 32; off > 0; off >>= 1)
        cnt += __shfl_down(cnt, off, 64);
    __shared__ int wsum[4];
    if ((threadIdx.x & 63) == 0) wsum[threadIdx.x >> 6] = cnt;
    __syncthreads();
    if (threadIdx.x == 0)
        partial[q * NB + b] = (float)(wsum[0] + wsum[1] + wsum[2] + wsum[3]);
}

// Kernel 2: out[chw] = sum_b (prev>0) * s_sum[b]. One float2 column per
// thread, 392 blocks x 256 threads = exact cover, unroll 32 -> 32 loads
// (256 B) outstanding per thread.
__global__ void __launch_bounds__(256)
corr_kernel(const float* __restrict__ prev, const float* __restrict__ partial,
            float* __restrict__ out) {
    __shared__ float s_sum[NB];
    const int t = threadIdx.x;
    if (t < NB) {
        float s = 0.f;
        #pragma unroll
        for (int q = 0; q < NSLICE; ++q)
            s += partial[q * NB + t];
        s_sum[t] = s;
    }
    __syncthreads();

    const int u = blockIdx.x * 256 + t;          // float2 column, 0..100351
    const float2* pv = reinterpret_cast<const float2*>(prev) + u;

    float2 acc = make_float2(0.f, 0.f);
    #pragma unroll 32
    for (int b = 0; b < NB; ++b) {
        const float2 v = pv[(size_t)b * PREV_V2];  // coalesced 8 B/lane
        const float s = s_sum[b];                  // wave-uniform broadcast
        acc.x += (v.x > 0.f) ? s : 0.f;
        acc.y += (v.y > 0.f) ? s : 0.f;
    }
    reinterpret_cast<float2*>(out)[u] = acc;       // single direct store
}

extern "C" void kernel_launch(void* const* d_in, const int* in_sizes, int n_in,
                              void* d_out, int out_size, void* d_ws, size_t ws_size,
                              hipStream_t stream) {
    const float* prev = (const float*)d_in[0];
    const float* curr = (const float*)d_in[1];
    float* out     = (float*)d_out;
    float* partial = (float*)d_ws;   // 1024 floats, written before read

    count_pos_kernel<<<dim3(NB, NSLICE), 256, 0, stream>>>(curr, partial);
    corr_kernel<<<PREV_V2 / 256, 256, 0, stream>>>(prev, partial, out);
}